// Round 1
// baseline (3708.805 us; speedup 1.0000x reference)
//
#include <hip/hip_runtime.h>
#include <stdint.h>

// Problem constants (reference: T=1000, N=64, H=1024, C=256)
#define T_STEPS 1000
#define NB      64
#define HDIM    1024
#define CDIM    256
#define G3      768          // 3*C
#define LOG2E   1.44269504088896340736f

typedef float f32x4  __attribute__((ext_vector_type(4)));
typedef short bf16x8 __attribute__((ext_vector_type(8)));   // 8 bf16 in 4 VGPRs (guide §3)

__device__ __forceinline__ float bf2f(unsigned short u) {
    union { unsigned int i; float f; } v; v.i = ((unsigned int)u) << 16; return v.f;
}
__device__ __forceinline__ unsigned short f2bf(float f) {
    union { float f; unsigned int i; } v; v.f = f;
    unsigned int r = v.i + 0x7fffu + ((v.i >> 16) & 1u);   // RNE
    return (unsigned short)(r >> 16);
}

// ---------------------------------------------------------------------------
// K0: convert W_ih [768,1024] and W_hh [768,256] fp32 -> bf16 into workspace
// ---------------------------------------------------------------------------
__global__ __launch_bounds__(256) void cvt_weights(
    const float* __restrict__ wih, const float* __restrict__ whh,
    unsigned short* __restrict__ wih_bf, unsigned short* __restrict__ whh_bf)
{
    int idx = blockIdx.x * 256 + threadIdx.x;          // grid covers exactly 983040
    if (idx < G3 * HDIM) {
        wih_bf[idx] = f2bf(wih[idx]);
    } else {
        int j = idx - G3 * HDIM;                       // < 196608 by grid sizing
        whh_bf[j] = f2bf(whh[j]);
    }
}

// ---------------------------------------------------------------------------
// K1: xp2[t][g][n] (bf16) = enc[t,n,:] . W_ih[g,:] + b_ih[g]
// Transposed (g-major, n-minor) layout so the scan's gate phase can load
// 4 consecutive batch rows as one ushort4.
// Block: 256 thr (4 waves). Tile: M=64 (== one timestep t), G=64, BK=64.
// ---------------------------------------------------------------------------
__global__ __launch_bounds__(256) void xproj_gemm(
    const float* __restrict__ enc,            // [64000,1024] fp32
    const unsigned short* __restrict__ wih,   // [768,1024] bf16
    const float* __restrict__ bih,            // [768] fp32
    unsigned short* __restrict__ xp2)         // [1000][768][64] bf16
{
    const int gt_base = blockIdx.x * 64;      // G-tile base (12 tiles)
    const int t       = blockIdx.y;           // M-tile == timestep (1000)
    const int tid  = threadIdx.x;
    const int w    = tid >> 6;                // wave 0..3 -> M rows [16w,16w+16)
    const int lane = tid & 63;
    const int q    = lane >> 4, l15 = lane & 15;

    // +8 pad breaks the 16-way bank aliasing of unpadded 64-col bf16 tiles
    __shared__ unsigned short As[64][72];
    __shared__ unsigned short Bs[64][72];

    const f32x4 zero4 = {0.f, 0.f, 0.f, 0.f};
    f32x4 acc[4] = {zero4, zero4, zero4, zero4};

    const int arow = tid >> 4;                // 0..15
    const int acol = (tid & 15) * 4;          // 0..60
    const int brow = tid >> 3;                // 0..31
    const int bcol = (tid & 7) * 8;           // 0..56

    for (int kt = 0; kt < 16; ++kt) {
        const int k0 = kt * 64;
        __syncthreads();                      // protect LDS reuse
        // stage A: 64x64 fp32 -> bf16 (fused convert; avoids an enc_bf16 copy)
        #pragma unroll
        for (int i = 0; i < 4; ++i) {
            const int r = arow + i * 16;
            const float4 av = *(const float4*)(enc + (size_t)(t * 64 + r) * HDIM + k0 + acol);
            ushort4 u;
            u.x = f2bf(av.x); u.y = f2bf(av.y); u.z = f2bf(av.z); u.w = f2bf(av.w);
            *(ushort4*)(&As[r][acol]) = u;
        }
        // stage B: 64x64 bf16 (pre-converted)
        #pragma unroll
        for (int i = 0; i < 2; ++i) {
            const int r = brow + i * 32;
            const uint4 bv = *(const uint4*)(wih + (size_t)(gt_base + r) * HDIM + k0 + bcol);
            *(uint4*)(&Bs[r][bcol]) = bv;
        }
        __syncthreads();
        // compute: per wave, 16 M-rows x 64 G-cols, BK=64 (2 MFMA-K steps)
        #pragma unroll
        for (int kk = 0; kk < 2; ++kk) {
            const bf16x8 a = *(const bf16x8*)(&As[16 * w + l15][kk * 32 + q * 8]);
            #pragma unroll
            for (int g = 0; g < 4; ++g) {
                const bf16x8 b = *(const bf16x8*)(&Bs[16 * g + l15][kk * 32 + q * 8]);
                acc[g] = __builtin_amdgcn_mfma_f32_16x16x32_bf16(a, b, acc[g], 0, 0, 0);
            }
        }
    }

    // epilogue: + b_ih, -> bf16, store transposed [t][g][n]
    // D-frag: col(in-tile)=l15, row=4q+r (m89/m91-verified mapping)
    #pragma unroll
    for (int g = 0; g < 4; ++g) {
        const int gg = gt_base + 16 * g + l15;
        const float bias = bih[gg];
        ushort4 u;
        u.x = f2bf(acc[g][0] + bias);
        u.y = f2bf(acc[g][1] + bias);
        u.z = f2bf(acc[g][2] + bias);
        u.w = f2bf(acc[g][3] + bias);
        *(ushort4*)(xp2 + ((size_t)t * G3 + gg) * 64 + 16 * w + 4 * q) = u;
    }
}

// ---------------------------------------------------------------------------
// K2: persistent GRU scan. 4 WGs x 1024 thr (16 waves); WG wg owns batch rows
// [16wg,16wg+16). Wave wv owns gtiles {wv,wv+16,wv+32} == gh columns
// {j, j+256, j+512} for j in [16wv,16wv+16): the exact (r,z,n) triplet needed
// for h_new columns [16wv,16wv+16) -> gates fully in-register, ONE barrier
// per step (double-buffered bf16 h in LDS). W_hh bf16 register-resident
// (96 VGPR/lane). h fp32 master in the gate-owner lanes' registers.
// ---------------------------------------------------------------------------
__global__ __launch_bounds__(1024) void gru_scan(
    const unsigned short* __restrict__ xp2,   // [1000][768][64] bf16
    const unsigned short* __restrict__ whh,   // [768][256] bf16
    const float* __restrict__ bhh,            // [768] fp32
    float* __restrict__ out)                  // [64000][256] fp32 (pre-softmax)
{
    const int wg   = blockIdx.x;              // 0..3
    const int tid  = threadIdx.x;
    const int wv   = tid >> 6;                // 0..15
    const int lane = tid & 63;
    const int q    = lane >> 4, l15 = lane & 15;
    const int jcol = wv * 16 + l15;           // owned h column 0..255

    __shared__ unsigned short hbuf[2][16][264];   // [buf][batch-row][C + 8 pad]

    // Preload W_hh fragments. B-frag for 16x16x32: B[n=lane&15][k=8q+j],
    // n maps to g = jcol + 256s, k contiguous in c -> one 16B load each.
    bf16x8 W[3][8];
    #pragma unroll
    for (int s = 0; s < 3; ++s)
        #pragma unroll
        for (int kk = 0; kk < 8; ++kk)
            W[s][kk] = *(const bf16x8*)(whh + (size_t)(jcol + 256 * s) * CDIM + kk * 32 + q * 8);

    const float bhr = bhh[jcol], bhz = bhh[jcol + 256], bhn = bhh[jcol + 512];

    float h[4] = {0.f, 0.f, 0.f, 0.f};        // h master: rows 4q+r, col jcol

    for (int i = tid; i < 2 * 16 * 264; i += 1024) ((unsigned short*)hbuf)[i] = 0;
    __syncthreads();

    const int nbase = wg * 16 + q * 4;        // global batch row of reg r=0
    int pb = 0;
    for (int t = 0; t < T_STEPS; ++t) {
        // xp loads for this step, issued up front: HBM latency (~900cyc)
        // hides under the MFMA phase (~1900cyc).
        const unsigned short* xpt = xp2 + (size_t)t * (G3 * 64) + nbase;
        const ushort4 xr4 = *(const ushort4*)(xpt + (size_t)jcol * 64);
        const ushort4 xz4 = *(const ushort4*)(xpt + (size_t)(jcol + 256) * 64);
        const ushort4 xn4 = *(const ushort4*)(xpt + (size_t)(jcol + 512) * 64);

        // matvec: gh(:, jcol + 256s) for s=r,z,n. A-frag A[m=l15][k=8q+j].
        f32x4 accr = {0.f, 0.f, 0.f, 0.f};
        f32x4 accz = {0.f, 0.f, 0.f, 0.f};
        f32x4 accn = {0.f, 0.f, 0.f, 0.f};
        #pragma unroll
        for (int kk = 0; kk < 8; ++kk) {
            const bf16x8 a = *(const bf16x8*)(&hbuf[pb][l15][kk * 32 + q * 8]);
            accr = __builtin_amdgcn_mfma_f32_16x16x32_bf16(a, W[0][kk], accr, 0, 0, 0);
            accz = __builtin_amdgcn_mfma_f32_16x16x32_bf16(a, W[1][kk], accz, 0, 0, 0);
            accn = __builtin_amdgcn_mfma_f32_16x16x32_bf16(a, W[2][kk], accn, 0, 0, 0);
        }

        const float xrf[4] = {bf2f(xr4.x), bf2f(xr4.y), bf2f(xr4.z), bf2f(xr4.w)};
        const float xzf[4] = {bf2f(xz4.x), bf2f(xz4.y), bf2f(xz4.z), bf2f(xz4.w)};
        const float xnf[4] = {bf2f(xn4.x), bf2f(xn4.y), bf2f(xn4.z), bf2f(xn4.w)};

        float* outp = out + (size_t)(t * NB + nbase) * CDIM + jcol;
        #pragma unroll
        for (int r = 0; r < 4; ++r) {
            // r = sigmoid(xr+hr); z = sigmoid(xz+hz); n = tanh(xn + r*hn)
            const float rg = __builtin_amdgcn_rcpf(
                1.f + __builtin_amdgcn_exp2f(-LOG2E * (xrf[r] + accr[r] + bhr)));
            const float ez = __builtin_amdgcn_exp2f(-LOG2E * (xzf[r] + accz[r] + bhz));
            const float zi = __builtin_amdgcn_rcpf(1.f + ez);     // z
            const float na = xnf[r] + rg * (accn[r] + bhn);
            const float e2 = __builtin_amdgcn_exp2f(2.f * LOG2E * na);
            const float th = 1.f - 2.f * __builtin_amdgcn_rcpf(e2 + 1.f);  // tanh, inf-safe
            const float hn = zi * (ez * th + h[r]);               // (1-z)*n + z*h
            h[r] = hn;
            outp[(size_t)r * CDIM] = hn;
            hbuf[pb ^ 1][q * 4 + r][jcol] = f2bf(hn);
        }
        __syncthreads();                      // publish hbuf[pb^1] for next step
        pb ^= 1;
    }
}

// ---------------------------------------------------------------------------
// K3: in-place log_softmax over C=256. One wave per row, 4 rows per block.
// ---------------------------------------------------------------------------
__global__ __launch_bounds__(256) void logsoftmax_rows(float* __restrict__ out)
{
    const int tid  = threadIdx.x;
    const int wv   = tid >> 6, lane = tid & 63;
    const int row  = blockIdx.x * 4 + wv;     // 0..63999
    float* p = out + (size_t)row * CDIM + lane * 4;
    float4 v = *(const float4*)p;

    float m = fmaxf(fmaxf(v.x, v.y), fmaxf(v.z, v.w));
    #pragma unroll
    for (int s = 32; s > 0; s >>= 1) m = fmaxf(m, __shfl_xor(m, s, 64));

    float sum = __builtin_amdgcn_exp2f((v.x - m) * LOG2E)
              + __builtin_amdgcn_exp2f((v.y - m) * LOG2E)
              + __builtin_amdgcn_exp2f((v.z - m) * LOG2E)
              + __builtin_amdgcn_exp2f((v.w - m) * LOG2E);
    #pragma unroll
    for (int s = 32; s > 0; s >>= 1) sum += __shfl_xor(sum, s, 64);

    const float lse = m + __builtin_amdgcn_logf(sum) * 0.69314718055994531f;
    v.x -= lse; v.y -= lse; v.z -= lse; v.w -= lse;
    *(float4*)p = v;
}

// ---------------------------------------------------------------------------
// Workspace layout (bytes):
//   xp2     @ 0          : 1000*768*64*2 = 98,304,000
//   wih_bf  @ 98,304,000 : 786,432*2     =  1,572,864
//   whh_bf  @ 99,876,864 : 196,608*2     =    393,216
// total ~100.3 MB
// ---------------------------------------------------------------------------
extern "C" void kernel_launch(void* const* d_in, const int* in_sizes, int n_in,
                              void* d_out, int out_size, void* d_ws, size_t ws_size,
                              hipStream_t stream)
{
    const float* enc = (const float*)d_in[0];   // [1000,64,1024]
    const float* wih = (const float*)d_in[1];   // [768,1024]
    const float* whh = (const float*)d_in[2];   // [768,256]
    const float* bih = (const float*)d_in[3];   // [768]
    const float* bhh = (const float*)d_in[4];   // [768]
    float* out = (float*)d_out;                 // [1000,64,256]

    unsigned short* xp2    = (unsigned short*)d_ws;
    unsigned short* wih_bf = (unsigned short*)((char*)d_ws + 98304000);
    unsigned short* whh_bf = (unsigned short*)((char*)d_ws + 99876864);

    cvt_weights<<<dim3(3840), dim3(256), 0, stream>>>(wih, whh, wih_bf, whh_bf);
    xproj_gemm<<<dim3(12, 1000), dim3(256), 0, stream>>>(enc, wih_bf, bih, xp2);
    gru_scan<<<dim3(4), dim3(1024), 0, stream>>>(xp2, whh_bf, bhh, out);
    logsoftmax_rows<<<dim3(16000), dim3(256), 0, stream>>>(out);
}

// Round 2
// 2964.750 us; speedup vs baseline: 1.2510x; 1.2510x over previous
//
#include <hip/hip_runtime.h>
#include <stdint.h>

// Problem constants (reference: T=1000, N=64, H=1024, C=256)
#define T_STEPS 1000
#define NB      64
#define HDIM    1024
#define CDIM    256
#define G3      768          // 3*C
#define LOG2E   1.44269504088896340736f

typedef float f32x4  __attribute__((ext_vector_type(4)));
typedef short bf16x8 __attribute__((ext_vector_type(8)));   // 8 bf16 in 4 VGPRs

__device__ __forceinline__ float bf2f(unsigned short u) {
    union { unsigned int i; float f; } v; v.i = ((unsigned int)u) << 16; return v.f;
}
__device__ __forceinline__ unsigned short f2bf(float f) {
    union { float f; unsigned int i; } v; v.f = f;
    unsigned int r = v.i + 0x7fffu + ((v.i >> 16) & 1u);   // RNE
    return (unsigned short)(r >> 16);
}

// ---------------------------------------------------------------------------
// K0: convert W_ih [768,1024] and W_hh [768,256] fp32 -> bf16 into workspace
// ---------------------------------------------------------------------------
__global__ __launch_bounds__(256) void cvt_weights(
    const float* __restrict__ wih, const float* __restrict__ whh,
    unsigned short* __restrict__ wih_bf, unsigned short* __restrict__ whh_bf)
{
    int idx = blockIdx.x * 256 + threadIdx.x;          // grid covers exactly 983040
    if (idx < G3 * HDIM) {
        wih_bf[idx] = f2bf(wih[idx]);
    } else {
        int j = idx - G3 * HDIM;                       // < 196608 by grid sizing
        whh_bf[j] = f2bf(whh[j]);
    }
}

// ---------------------------------------------------------------------------
// K1: xp2[t][w][g][n16] (bf16) = enc[t,16w+n16,:] . W_ih[g,:] + b_ih[g]
// WG-blocked layout: the scan's WG `wg` reads only the [t][wg][*][*] slab,
// which is fully dense (512-B segments) -> no sector over-fetch.
// Block: 256 thr (4 waves). Tile: M=64 (== one timestep t), G=64, BK=64.
// ---------------------------------------------------------------------------
__global__ __launch_bounds__(256) void xproj_gemm(
    const float* __restrict__ enc,            // [64000,1024] fp32
    const unsigned short* __restrict__ wih,   // [768,1024] bf16
    const float* __restrict__ bih,            // [768] fp32
    unsigned short* __restrict__ xp2)         // [1000][4][768][16] bf16
{
    const int gt_base = blockIdx.x * 64;      // G-tile base (12 tiles)
    const int t       = blockIdx.y;           // M-tile == timestep (1000)
    const int tid  = threadIdx.x;
    const int w    = tid >> 6;                // wave 0..3 -> M rows [16w,16w+16)
    const int lane = tid & 63;
    const int q    = lane >> 4, l15 = lane & 15;

    // +8 pad breaks the 16-way bank aliasing of unpadded 64-col bf16 tiles
    __shared__ unsigned short As[64][72];
    __shared__ unsigned short Bs[64][72];

    const f32x4 zero4 = {0.f, 0.f, 0.f, 0.f};
    f32x4 acc[4] = {zero4, zero4, zero4, zero4};

    const int arow = tid >> 4;                // 0..15
    const int acol = (tid & 15) * 4;          // 0..60
    const int brow = tid >> 3;                // 0..31
    const int bcol = (tid & 7) * 8;           // 0..56

    for (int kt = 0; kt < 16; ++kt) {
        const int k0 = kt * 64;
        __syncthreads();                      // protect LDS reuse
        // stage A: 64x64 fp32 -> bf16 (fused convert)
        #pragma unroll
        for (int i = 0; i < 4; ++i) {
            const int r = arow + i * 16;
            const float4 av = *(const float4*)(enc + (size_t)(t * 64 + r) * HDIM + k0 + acol);
            ushort4 u;
            u.x = f2bf(av.x); u.y = f2bf(av.y); u.z = f2bf(av.z); u.w = f2bf(av.w);
            *(ushort4*)(&As[r][acol]) = u;
        }
        // stage B: 64x64 bf16 (pre-converted)
        #pragma unroll
        for (int i = 0; i < 2; ++i) {
            const int r = brow + i * 32;
            const uint4 bv = *(const uint4*)(wih + (size_t)(gt_base + r) * HDIM + k0 + bcol);
            *(uint4*)(&Bs[r][bcol]) = bv;
        }
        __syncthreads();
        // compute: per wave, 16 M-rows x 64 G-cols, BK=64 (2 MFMA-K steps)
        #pragma unroll
        for (int kk = 0; kk < 2; ++kk) {
            const bf16x8 a = *(const bf16x8*)(&As[16 * w + l15][kk * 32 + q * 8]);
            #pragma unroll
            for (int g = 0; g < 4; ++g) {
                const bf16x8 b = *(const bf16x8*)(&Bs[16 * g + l15][kk * 32 + q * 8]);
                acc[g] = __builtin_amdgcn_mfma_f32_16x16x32_bf16(a, b, acc[g], 0, 0, 0);
            }
        }
    }

    // epilogue: + b_ih, -> bf16, store WG-blocked [t][w][g][n16]
    // D-frag: col(in-tile)=l15, row(batch)=4q+r
    #pragma unroll
    for (int g = 0; g < 4; ++g) {
        const int gg = gt_base + 16 * g + l15;
        const float bias = bih[gg];
        ushort4 u;
        u.x = f2bf(acc[g][0] + bias);
        u.y = f2bf(acc[g][1] + bias);
        u.z = f2bf(acc[g][2] + bias);
        u.w = f2bf(acc[g][3] + bias);
        *(ushort4*)(xp2 + ((size_t)(t * 4 + w) * G3 + gg) * 16 + 4 * q) = u;
    }
}

// ---------------------------------------------------------------------------
// K2: persistent GRU scan. 4 WGs x 512 thr (8 waves = 2 waves/SIMD so the
// 256-VGPR cap holds the weights). WG wg owns batch rows [16wg,16wg+16).
// Wave wv owns h col-tiles {2wv, 2wv+1}; for col-tile c the gate gh-tiles
// are {c, c+16, c+32} == gh cols {j, j+256, j+512}, j in [16c,16c+16).
// W_hh slice register-resident: 2 tiles x 3 gates x 8 ksteps = 48 bf16x8
// = 192 VGPR/lane. Gates fully in-register; ONE barrier per step with
// double-buffered bf16 h in LDS. h fp32 master in owning lanes.
// ---------------------------------------------------------------------------
__global__ __launch_bounds__(512, 2) void gru_scan(
    const unsigned short* __restrict__ xp2,   // [1000][4][768][16] bf16
    const unsigned short* __restrict__ whh,   // [768][256] bf16
    const float* __restrict__ bhh,            // [768] fp32
    float* __restrict__ out)                  // [64000][256] fp32 (pre-softmax)
{
    const int wg   = blockIdx.x;              // 0..3
    const int tid  = threadIdx.x;
    const int wv   = tid >> 6;                // 0..7
    const int lane = tid & 63;
    const int q    = lane >> 4, l15 = lane & 15;

    __shared__ unsigned short hbuf[2][16][264];   // [buf][batch-row][C + 8 pad]

    // Preload W_hh fragments. B-frag for 16x16x32: B[n=l15][k=8q+j];
    // n maps to gh-col g, k contiguous in c -> one 16B load each.
    bf16x8 W[2][3][8];
    float  bh[2][3];
    #pragma unroll
    for (int c = 0; c < 2; ++c)
        #pragma unroll
        for (int s = 0; s < 3; ++s) {
            const int g = 32 * wv + 16 * c + 256 * s + l15;
            bh[c][s] = bhh[g];
            #pragma unroll
            for (int kk = 0; kk < 8; ++kk)
                W[c][s][kk] = *(const bf16x8*)(whh + (size_t)g * CDIM + kk * 32 + q * 8);
        }

    float h[2][4] = {{0.f,0.f,0.f,0.f},{0.f,0.f,0.f,0.f}};  // rows 4q+r, col jc

    for (int i = tid; i < 2 * 16 * 264; i += 512) ((unsigned short*)hbuf)[i] = 0;
    __syncthreads();

    int pb = 0;
    for (int t = 0; t < T_STEPS; ++t) {
        // xp loads for this step issued up front: L3 latency hides under MFMAs
        const unsigned short* xpt = xp2 + (size_t)(t * 4 + wg) * (G3 * 16);
        ushort4 x[2][3];
        #pragma unroll
        for (int c = 0; c < 2; ++c)
            #pragma unroll
            for (int s = 0; s < 3; ++s)
                x[c][s] = *(const ushort4*)(xpt + (size_t)(32 * wv + 16 * c + 256 * s + l15) * 16 + 4 * q);

        // matvec: 6 gh-tiles per wave. A-frag A[m=l15][k=8q+j] shared.
        f32x4 acc[2][3];
        #pragma unroll
        for (int c = 0; c < 2; ++c)
            #pragma unroll
            for (int s = 0; s < 3; ++s) acc[c][s] = (f32x4){0.f,0.f,0.f,0.f};
        #pragma unroll
        for (int kk = 0; kk < 8; ++kk) {
            const bf16x8 a = *(const bf16x8*)(&hbuf[pb][l15][kk * 32 + q * 8]);
            #pragma unroll
            for (int c = 0; c < 2; ++c) {
                acc[c][0] = __builtin_amdgcn_mfma_f32_16x16x32_bf16(a, W[c][0][kk], acc[c][0], 0, 0, 0);
                acc[c][1] = __builtin_amdgcn_mfma_f32_16x16x32_bf16(a, W[c][1][kk], acc[c][1], 0, 0, 0);
                acc[c][2] = __builtin_amdgcn_mfma_f32_16x16x32_bf16(a, W[c][2][kk], acc[c][2], 0, 0, 0);
            }
        }

        float* outt = out + (size_t)(t * NB + wg * 16 + q * 4) * CDIM;
        #pragma unroll
        for (int c = 0; c < 2; ++c) {
            const int jc = 32 * wv + 16 * c + l15;       // owned h column
            const unsigned short* xr = (const unsigned short*)&x[c][0];
            const unsigned short* xz = (const unsigned short*)&x[c][1];
            const unsigned short* xn = (const unsigned short*)&x[c][2];
            #pragma unroll
            for (int r = 0; r < 4; ++r) {
                // r = sigmoid(xr+hr); z = sigmoid(xz+hz); n = tanh(xn + r*hn)
                const float rg = __builtin_amdgcn_rcpf(
                    1.f + __builtin_amdgcn_exp2f(-LOG2E * (bf2f(xr[r]) + acc[c][0][r] + bh[c][0])));
                const float ez = __builtin_amdgcn_exp2f(-LOG2E * (bf2f(xz[r]) + acc[c][1][r] + bh[c][1]));
                const float zi = __builtin_amdgcn_rcpf(1.f + ez);     // z
                const float na = bf2f(xn[r]) + rg * (acc[c][2][r] + bh[c][2]);
                const float e2 = __builtin_amdgcn_exp2f(2.f * LOG2E * na);
                const float th = 1.f - 2.f * __builtin_amdgcn_rcpf(e2 + 1.f);  // tanh
                const float hn = zi * (ez * th + h[c][r]);            // (1-z)*n + z*h
                h[c][r] = hn;
                outt[(size_t)r * CDIM + jc] = hn;
                hbuf[pb ^ 1][q * 4 + r][jc] = f2bf(hn);
            }
        }
        __syncthreads();                      // publish hbuf[pb^1] for next step
        pb ^= 1;
    }
}

// ---------------------------------------------------------------------------
// K3: in-place log_softmax over C=256. One wave per row, 4 rows per block.
// ---------------------------------------------------------------------------
__global__ __launch_bounds__(256) void logsoftmax_rows(float* __restrict__ out)
{
    const int tid  = threadIdx.x;
    const int wv   = tid >> 6, lane = tid & 63;
    const int row  = blockIdx.x * 4 + wv;     // 0..63999
    float* p = out + (size_t)row * CDIM + lane * 4;
    float4 v = *(const float4*)p;

    float m = fmaxf(fmaxf(v.x, v.y), fmaxf(v.z, v.w));
    #pragma unroll
    for (int s = 32; s > 0; s >>= 1) m = fmaxf(m, __shfl_xor(m, s, 64));

    float sum = __builtin_amdgcn_exp2f((v.x - m) * LOG2E)
              + __builtin_amdgcn_exp2f((v.y - m) * LOG2E)
              + __builtin_amdgcn_exp2f((v.z - m) * LOG2E)
              + __builtin_amdgcn_exp2f((v.w - m) * LOG2E);
    #pragma unroll
    for (int s = 32; s > 0; s >>= 1) sum += __shfl_xor(sum, s, 64);

    const float lse = m + __builtin_amdgcn_logf(sum) * 0.69314718055994531f;
    v.x -= lse; v.y -= lse; v.z -= lse; v.w -= lse;
    *(float4*)p = v;
}

// ---------------------------------------------------------------------------
// Workspace layout (bytes):
//   xp2     @ 0          : 1000*768*64*2 = 98,304,000
//   wih_bf  @ 98,304,000 : 786,432*2     =  1,572,864
//   whh_bf  @ 99,876,864 : 196,608*2     =    393,216
// ---------------------------------------------------------------------------
extern "C" void kernel_launch(void* const* d_in, const int* in_sizes, int n_in,
                              void* d_out, int out_size, void* d_ws, size_t ws_size,
                              hipStream_t stream)
{
    const float* enc = (const float*)d_in[0];   // [1000,64,1024]
    const float* wih = (const float*)d_in[1];   // [768,1024]
    const float* whh = (const float*)d_in[2];   // [768,256]
    const float* bih = (const float*)d_in[3];   // [768]
    const float* bhh = (const float*)d_in[4];   // [768]
    float* out = (float*)d_out;                 // [1000,64,256]

    unsigned short* xp2    = (unsigned short*)d_ws;
    unsigned short* wih_bf = (unsigned short*)((char*)d_ws + 98304000);
    unsigned short* whh_bf = (unsigned short*)((char*)d_ws + 99876864);

    cvt_weights<<<dim3(3840), dim3(256), 0, stream>>>(wih, whh, wih_bf, whh_bf);
    xproj_gemm<<<dim3(12, 1000), dim3(256), 0, stream>>>(enc, wih_bf, bih, xp2);
    gru_scan<<<dim3(4), dim3(512), 0, stream>>>(xp2, whh_bf, bhh, out);
    logsoftmax_rows<<<dim3(16000), dim3(256), 0, stream>>>(out);
}

// Round 3
// 2023.095 us; speedup vs baseline: 1.8332x; 1.4655x over previous
//
#include <hip/hip_runtime.h>
#include <stdint.h>

// Problem constants (reference: T=1000, N=64, H=1024, C=256)
#define T_STEPS 1000
#define NB      64
#define HDIM    1024
#define CDIM    256
#define G3      768          // 3*C
#define LOG2E   1.44269504088896340736f

typedef float f32x4  __attribute__((ext_vector_type(4)));
typedef short bf16x8 __attribute__((ext_vector_type(8)));   // 8 bf16 in 4 VGPRs
typedef int   i32x4  __attribute__((ext_vector_type(4)));   // 16 int8 in 4 VGPRs

__device__ __forceinline__ float bf2f(unsigned short u) {
    union { unsigned int i; float f; } v; v.i = ((unsigned int)u) << 16; return v.f;
}
__device__ __forceinline__ unsigned short f2bf(float f) {
    union { float f; unsigned int i; } v; v.f = f;
    unsigned int r = v.i + 0x7fffu + ((v.i >> 16) & 1u);   // RNE
    return (unsigned short)(r >> 16);
}

// ---------------------------------------------------------------------------
// K0: convert W_ih [768,1024] fp32 -> bf16
// ---------------------------------------------------------------------------
__global__ __launch_bounds__(256) void cvt_wih(
    const float* __restrict__ wih, unsigned short* __restrict__ wih_bf)
{
    int idx = blockIdx.x * 256 + threadIdx.x;          // grid covers exactly 786432
    wih_bf[idx] = f2bf(wih[idx]);
}

// ---------------------------------------------------------------------------
// K0b: per-row symmetric int8 quantization of W_hh [768,256].
// Wq[g,c] = rint(W[g,c] * 127/rowmax); dscale[g] = rowmax/(127*127) so that
// gh = dscale[g] * sum(hq * Wq) with hq = rint(127*h).
// One wave per row.
// ---------------------------------------------------------------------------
__global__ __launch_bounds__(64) void quant_whh(
    const float* __restrict__ whh, signed char* __restrict__ wq,
    float* __restrict__ dscale)
{
    const int g    = blockIdx.x;          // 0..767
    const int lane = threadIdx.x;         // 0..63
    const float4 w = *(const float4*)(whh + (size_t)g * CDIM + lane * 4);
    float m = fmaxf(fmaxf(fabsf(w.x), fabsf(w.y)), fmaxf(fabsf(w.z), fabsf(w.w)));
    #pragma unroll
    for (int s = 32; s > 0; s >>= 1) m = fmaxf(m, __shfl_xor(m, s, 64));
    const float inv = (m > 0.f) ? 127.f / m : 0.f;
    char4 q;
    q.x = (signed char)(int)rintf(w.x * inv);
    q.y = (signed char)(int)rintf(w.y * inv);
    q.z = (signed char)(int)rintf(w.z * inv);
    q.w = (signed char)(int)rintf(w.w * inv);
    *(char4*)(wq + (size_t)g * CDIM + lane * 4) = q;
    if (lane == 0) dscale[g] = m / (127.f * 127.f);
}

// ---------------------------------------------------------------------------
// K1: xp2[t][w][g][n16] (bf16) = enc[t,16w+n16,:] . W_ih[g,:] + b_ih[g]
// WG-blocked layout (dense per-scan-WG slabs). 256 thr, M=64,G=64,BK=64.
// ---------------------------------------------------------------------------
__global__ __launch_bounds__(256) void xproj_gemm(
    const float* __restrict__ enc,            // [64000,1024] fp32
    const unsigned short* __restrict__ wih,   // [768,1024] bf16
    const float* __restrict__ bih,            // [768] fp32
    unsigned short* __restrict__ xp2)         // [1000][4][768][16] bf16
{
    const int gt_base = blockIdx.x * 64;      // G-tile base (12 tiles)
    const int t       = blockIdx.y;           // M-tile == timestep (1000)
    const int tid  = threadIdx.x;
    const int w    = tid >> 6;                // wave 0..3 -> M rows [16w,16w+16)
    const int lane = tid & 63;
    const int q    = lane >> 4, l15 = lane & 15;

    __shared__ unsigned short As[64][72];
    __shared__ unsigned short Bs[64][72];

    const f32x4 zero4 = {0.f, 0.f, 0.f, 0.f};
    f32x4 acc[4] = {zero4, zero4, zero4, zero4};

    const int arow = tid >> 4;                // 0..15
    const int acol = (tid & 15) * 4;          // 0..60
    const int brow = tid >> 3;                // 0..31
    const int bcol = (tid & 7) * 8;           // 0..56

    for (int kt = 0; kt < 16; ++kt) {
        const int k0 = kt * 64;
        __syncthreads();
        #pragma unroll
        for (int i = 0; i < 4; ++i) {
            const int r = arow + i * 16;
            const float4 av = *(const float4*)(enc + (size_t)(t * 64 + r) * HDIM + k0 + acol);
            ushort4 u;
            u.x = f2bf(av.x); u.y = f2bf(av.y); u.z = f2bf(av.z); u.w = f2bf(av.w);
            *(ushort4*)(&As[r][acol]) = u;
        }
        #pragma unroll
        for (int i = 0; i < 2; ++i) {
            const int r = brow + i * 32;
            const uint4 bv = *(const uint4*)(wih + (size_t)(gt_base + r) * HDIM + k0 + bcol);
            *(uint4*)(&Bs[r][bcol]) = bv;
        }
        __syncthreads();
        #pragma unroll
        for (int kk = 0; kk < 2; ++kk) {
            const bf16x8 a = *(const bf16x8*)(&As[16 * w + l15][kk * 32 + q * 8]);
            #pragma unroll
            for (int g = 0; g < 4; ++g) {
                const bf16x8 b = *(const bf16x8*)(&Bs[16 * g + l15][kk * 32 + q * 8]);
                acc[g] = __builtin_amdgcn_mfma_f32_16x16x32_bf16(a, b, acc[g], 0, 0, 0);
            }
        }
    }

    #pragma unroll
    for (int g = 0; g < 4; ++g) {
        const int gg = gt_base + 16 * g + l15;
        const float bias = bih[gg];
        ushort4 u;
        u.x = f2bf(acc[g][0] + bias);
        u.y = f2bf(acc[g][1] + bias);
        u.z = f2bf(acc[g][2] + bias);
        u.w = f2bf(acc[g][3] + bias);
        *(ushort4*)(xp2 + ((size_t)(t * 4 + w) * G3 + gg) * 16 + 4 * q) = u;
    }
}

// ---------------------------------------------------------------------------
// K2: persistent GRU scan, int8 recurrent matvec.
// 4 WGs x 512 thr (8 waves). WG wg owns batch rows [16wg,16wg+16).
// Wave wv owns h col-tiles {2wv,2wv+1}; per tile the (r,z,n) gh-tiles are
// computed in-register. W_hh int8 register-resident: 2x3x4 i32x4 = 96 VGPR,
// pinned via empty asm (non-rematerializable defs). h int8 in LDS,
// double-buffered; ONE lgkm-only barrier per step (out-stores / xp prefetch
// are lane-private -> no vmcnt drain needed). xp prefetched 1 step ahead.
// ---------------------------------------------------------------------------
__global__ void __launch_bounds__(512)
__attribute__((amdgpu_waves_per_eu(2, 2)))
gru_scan(
    const unsigned short* __restrict__ xp2,   // [1000][4][768][16] bf16
    const signed char* __restrict__ wq,       // [768][256] int8
    const float* __restrict__ dscale,         // [768] fp32
    const float* __restrict__ bhh,            // [768] fp32
    float* __restrict__ out)                  // [64000][256] fp32 (pre-softmax)
{
    const int wg   = blockIdx.x;              // 0..3
    const int tid  = threadIdx.x;
    const int wv   = tid >> 6;                // 0..7
    const int lane = tid & 63;
    const int q    = lane >> 4, l15 = lane & 15;

    // row stride 304 B (19*16): 16B-aligned rows, start-bank spread for b128
    __shared__ __align__(16) signed char hbuf[2][16][304];

    // Preload int8 W fragments. B-frag for 16x16x64 i8: B[n=l15][k=16q+j],
    // k contiguous in c -> one 16B load each.
    i32x4 W[2][3][4];
    float d[2][3], bh[2][3];
    #pragma unroll
    for (int c = 0; c < 2; ++c)
        #pragma unroll
        for (int s = 0; s < 3; ++s) {
            const int g = 16 * (2 * wv + c) + 256 * s + l15;
            d[c][s]  = dscale[g];
            bh[c][s] = bhh[g];
            #pragma unroll
            for (int kk = 0; kk < 4; ++kk)
                W[c][s][kk] = *(const i32x4*)(wq + (size_t)g * CDIM + kk * 64 + q * 16);
        }
    // Pin: asm defs are not rematerializable -> RA must keep these in VGPRs.
    #pragma unroll
    for (int c = 0; c < 2; ++c)
        #pragma unroll
        for (int s = 0; s < 3; ++s)
            asm volatile("" : "+v"(W[c][s][0]), "+v"(W[c][s][1]),
                              "+v"(W[c][s][2]), "+v"(W[c][s][3]));

    float h[2][4] = {{0.f,0.f,0.f,0.f},{0.f,0.f,0.f,0.f}};  // rows 4q+r, col jc

    for (int i = tid; i < 2 * 16 * 304; i += 512) ((signed char*)hbuf)[i] = 0;
    __syncthreads();

    // xp prefetch for t=0
    ushort4 xc[2][3];
    {
        const unsigned short* xpt = xp2 + (size_t)(0 * 4 + wg) * (G3 * 16);
        #pragma unroll
        for (int c = 0; c < 2; ++c)
            #pragma unroll
            for (int s = 0; s < 3; ++s)
                xc[c][s] = *(const ushort4*)(xpt + (size_t)(16 * (2 * wv + c) + 256 * s + l15) * 16 + 4 * q);
    }

    int pb = 0;
    for (int t = 0; t < T_STEPS; ++t) {
        // prefetch xp for t+1 (latency hides under MFMA + gate phase)
        const int tn = (t + 1 < T_STEPS) ? t + 1 : t;
        ushort4 xn[2][3];
        {
            const unsigned short* xpt = xp2 + (size_t)(tn * 4 + wg) * (G3 * 16);
            #pragma unroll
            for (int c = 0; c < 2; ++c)
                #pragma unroll
                for (int s = 0; s < 3; ++s)
                    xn[c][s] = *(const ushort4*)(xpt + (size_t)(16 * (2 * wv + c) + 256 * s + l15) * 16 + 4 * q);
        }

        // int8 matvec: 6 gh-tiles per wave. A-frag A[m=l15][k=16q+j] shared.
        i32x4 acc[2][3];
        #pragma unroll
        for (int c = 0; c < 2; ++c)
            #pragma unroll
            for (int s = 0; s < 3; ++s) acc[c][s] = (i32x4){0, 0, 0, 0};
        #pragma unroll
        for (int kk = 0; kk < 4; ++kk) {
            const i32x4 a = *(const i32x4*)(&hbuf[pb][l15][kk * 64 + q * 16]);
            #pragma unroll
            for (int c = 0; c < 2; ++c) {
                acc[c][0] = __builtin_amdgcn_mfma_i32_16x16x64_i8(a, W[c][0][kk], acc[c][0], 0, 0, 0);
                acc[c][1] = __builtin_amdgcn_mfma_i32_16x16x64_i8(a, W[c][1][kk], acc[c][1], 0, 0, 0);
                acc[c][2] = __builtin_amdgcn_mfma_i32_16x16x64_i8(a, W[c][2][kk], acc[c][2], 0, 0, 0);
            }
        }

        float* outt = out + (size_t)(t * NB + wg * 16 + q * 4) * CDIM;
        const int pbn = pb ^ 1;
        #pragma unroll
        for (int c = 0; c < 2; ++c) {
            const int jc = 16 * (2 * wv + c) + l15;       // owned h column
            const unsigned short* xr = (const unsigned short*)&xc[c][0];
            const unsigned short* xz = (const unsigned short*)&xc[c][1];
            const unsigned short* xnw = (const unsigned short*)&xc[c][2];
            #pragma unroll
            for (int r = 0; r < 4; ++r) {
                const float a_r = fmaf(d[c][0], (float)acc[c][0][r], bf2f(xr[r]) + bh[c][0]);
                const float rg  = __builtin_amdgcn_rcpf(
                    1.f + __builtin_amdgcn_exp2f(-LOG2E * a_r));
                const float a_z = fmaf(d[c][1], (float)acc[c][1][r], bf2f(xz[r]) + bh[c][1]);
                const float ez  = __builtin_amdgcn_exp2f(-LOG2E * a_z);
                const float zi  = __builtin_amdgcn_rcpf(1.f + ez);     // = z
                const float hng = fmaf(d[c][2], (float)acc[c][2][r], bh[c][2]);
                const float na  = fmaf(rg, hng, bf2f(xnw[r]));
                const float e2  = __builtin_amdgcn_exp2f(2.f * LOG2E * na);
                const float th  = 1.f - 2.f * __builtin_amdgcn_rcpf(e2 + 1.f);  // tanh
                const float hv  = zi * fmaf(ez, th, h[c][r]);          // (1-z)n + zh
                h[c][r] = hv;
                outt[(size_t)r * CDIM + jc] = hv;
                hbuf[pbn][4 * q + r][jc] = (signed char)(int)rintf(hv * 127.f);
            }
        }
        // lgkm-only barrier: publish hbuf[pbn]; skip vmcnt(0) drain (out
        // stores + xp prefetch are lane-private, no cross-wave global deps)
        asm volatile("s_waitcnt lgkmcnt(0)\n\ts_barrier" ::: "memory");
        pb = pbn;
        #pragma unroll
        for (int c = 0; c < 2; ++c)
            #pragma unroll
            for (int s = 0; s < 3; ++s) xc[c][s] = xn[c][s];
    }
}

// ---------------------------------------------------------------------------
// K3: in-place log_softmax over C=256. One wave per row, 4 rows per block.
// ---------------------------------------------------------------------------
__global__ __launch_bounds__(256) void logsoftmax_rows(float* __restrict__ out)
{
    const int tid  = threadIdx.x;
    const int wv   = tid >> 6, lane = tid & 63;
    const int row  = blockIdx.x * 4 + wv;     // 0..63999
    float* p = out + (size_t)row * CDIM + lane * 4;
    float4 v = *(const float4*)p;

    float m = fmaxf(fmaxf(v.x, v.y), fmaxf(v.z, v.w));
    #pragma unroll
    for (int s = 32; s > 0; s >>= 1) m = fmaxf(m, __shfl_xor(m, s, 64));

    float sum = __builtin_amdgcn_exp2f((v.x - m) * LOG2E)
              + __builtin_amdgcn_exp2f((v.y - m) * LOG2E)
              + __builtin_amdgcn_exp2f((v.z - m) * LOG2E)
              + __builtin_amdgcn_exp2f((v.w - m) * LOG2E);
    #pragma unroll
    for (int s = 32; s > 0; s >>= 1) sum += __shfl_xor(sum, s, 64);

    const float lse = m + __builtin_amdgcn_logf(sum) * 0.69314718055994531f;
    v.x -= lse; v.y -= lse; v.z -= lse; v.w -= lse;
    *(float4*)p = v;
}

// ---------------------------------------------------------------------------
// Workspace layout (bytes):
//   xp2     @ 0           : 1000*768*64*2 = 98,304,000
//   wih_bf  @ 98,304,000  : 786,432*2     =  1,572,864
//   whhq    @ 99,876,864  : 196,608       =    196,608
//   dscale  @ 100,073,472 : 768*4         =      3,072
// ---------------------------------------------------------------------------
extern "C" void kernel_launch(void* const* d_in, const int* in_sizes, int n_in,
                              void* d_out, int out_size, void* d_ws, size_t ws_size,
                              hipStream_t stream)
{
    const float* enc = (const float*)d_in[0];   // [1000,64,1024]
    const float* wih = (const float*)d_in[1];   // [768,1024]
    const float* whh = (const float*)d_in[2];   // [768,256]
    const float* bih = (const float*)d_in[3];   // [768]
    const float* bhh = (const float*)d_in[4];   // [768]
    float* out = (float*)d_out;                 // [1000,64,256]

    unsigned short* xp2    = (unsigned short*)d_ws;
    unsigned short* wih_bf = (unsigned short*)((char*)d_ws + 98304000);
    signed char*    whhq   = (signed char*)((char*)d_ws + 99876864);
    float*          dsc    = (float*)((char*)d_ws + 100073472);

    cvt_wih<<<dim3(3072), dim3(256), 0, stream>>>(wih, wih_bf);
    quant_whh<<<dim3(768), dim3(64), 0, stream>>>(whh, whhq, dsc);
    xproj_gemm<<<dim3(12, 1000), dim3(256), 0, stream>>>(enc, wih_bf, bih, xp2);
    gru_scan<<<dim3(4), dim3(512), 0, stream>>>(xp2, whhq, dsc, bhh, out);
    logsoftmax_rows<<<dim3(16000), dim3(256), 0, stream>>>(out);
}